// Round 4
// baseline (576.765 us; speedup 1.0000x reference)
//
#include <hip/hip_runtime.h>

#define N_NODES 100000
#define N_EDGES 1600000
#define DIN 64
#define DOUT 32
#define NEG_SLOPE 0.01f
#define NBLK ((N_NODES + 255) / 256)   // 391
#define NBUCK ((N_NODES + 511) / 512)  // 196 buckets of 512 nodes
#define NSTRM 8                        // append streams per bucket (~XCDs)
#define CAP 2048                       // capacity per (bucket,stream); mean ~1020, std ~32

// ---------------- CSR build ----------------
__global__ void zero_kernel(int* __restrict__ cnt, int* __restrict__ subfill) {
    int i = blockIdx.x * blockDim.x + threadIdx.x;
    if (i < N_NODES) cnt[i] = 0;
    if (i < NBUCK * NSTRM) subfill[i] = 0;
}

__global__ void count_kernel(const int* __restrict__ dst, int* __restrict__ cnt) {
    int e = blockIdx.x * blockDim.x + threadIdx.x;
    if (e < N_EDGES) atomicAdd(&cnt[dst[e]], 1);
}

// phase A: per-block sums of cnt
__global__ void blocksum_kernel(const int* __restrict__ cnt, int* __restrict__ bsum) {
    int i = blockIdx.x * 256 + threadIdx.x;
    int v = (i < N_NODES) ? cnt[i] : 0;
#pragma unroll
    for (int off = 32; off; off >>= 1) v += __shfl_down(v, off);
    __shared__ int ws[4];
    if ((threadIdx.x & 63) == 0) ws[threadIdx.x >> 6] = v;
    __syncthreads();
    if (threadIdx.x == 0) bsum[blockIdx.x] = ws[0] + ws[1] + ws[2] + ws[3];
}

// phase B: exclusive scan of the 391 block sums
__global__ __launch_bounds__(512) void scan_bsum_kernel(const int* __restrict__ bsum,
                                                        int* __restrict__ bofs) {
    __shared__ int sh[512];
    int t = threadIdx.x;
    int v = (t < NBLK) ? bsum[t] : 0;
    sh[t] = v;
    __syncthreads();
    for (int off = 1; off < 512; off <<= 1) {
        int a = sh[t];
        int add = (t >= off) ? sh[t - off] : 0;
        __syncthreads();
        sh[t] = a + add;
        __syncthreads();
    }
    if (t < NBLK) bofs[t] = sh[t] - v;  // exclusive
}

// phase C: in-block exclusive scan + block offset -> rowptr; also dinv
__global__ void rowptr_kernel(const int* __restrict__ cnt, const int* __restrict__ bofs,
                              int* __restrict__ rowptr, float* __restrict__ dinv) {
    int i = blockIdx.x * 256 + threadIdx.x;
    int v = (i < N_NODES) ? cnt[i] : 0;
    int lane = threadIdx.x & 63;
    int w = threadIdx.x >> 6;
    int x = v;
#pragma unroll
    for (int off = 1; off < 64; off <<= 1) {
        int n = __shfl_up(x, off);
        if (lane >= off) x += n;
    }
    __shared__ int wtot[4];
    if (lane == 63) wtot[w] = x;
    __syncthreads();
    int wofs = 0;
    for (int k = 0; k < w; ++k) wofs += wtot[k];
    int excl = x - v + wofs + bofs[blockIdx.x];
    if (i < N_NODES) {
        rowptr[i] = excl;
        dinv[i] = rsqrtf((float)(v + 1));
        if (i == N_NODES - 1) rowptr[N_NODES] = excl + v;
    }
}

// bin pass 1: append packed edges to per-(bucket,stream) staging regions.
// stream = blockIdx&7 ~ XCD (round-robin dispatch) -> line written by one XCD, densely.
__global__ void binpass1_kernel(const int* __restrict__ src, const int* __restrict__ dst,
                                int* __restrict__ subfill, unsigned int* __restrict__ tmp) {
    int e = blockIdx.x * 256 + threadIdx.x;
    if (e >= N_EDGES) return;
    int d = dst[e];
    int b = d >> 9;
    int strm = blockIdx.x & (NSTRM - 1);
    unsigned int payload = (unsigned int)src[e] | ((unsigned int)(d & 511) << 17);
    int slot = b * NSTRM + strm;
    int idx = atomicAdd(&subfill[slot], 1);
    if (idx < CAP) tmp[(size_t)slot * CAP + idx] = payload;
}

// bin pass 2: one block per bucket; LDS fill cursors; exact CSR placement.
__global__ __launch_bounds__(256) void binpass2_kernel(const unsigned int* __restrict__ tmp,
                                                       const int* __restrict__ subfill,
                                                       const int* __restrict__ rowptr,
                                                       int* __restrict__ colsrc) {
    __shared__ int posl[512];
    int b = blockIdx.x;
    int base_node = b << 9;
    int nn = min(512, N_NODES - base_node);
    for (int i = threadIdx.x; i < nn; i += 256) posl[i] = rowptr[base_node + i];
    __syncthreads();
    for (int s = 0; s < NSTRM; ++s) {
        int slot = b * NSTRM + s;
        int len = min(subfill[slot], CAP);
        const unsigned int* p = tmp + (size_t)slot * CAP;
        for (int i = threadIdx.x; i < len; i += 256) {
            unsigned int e = p[i];
            int srcv = (int)(e & 0x1FFFFu);
            int dlow = (int)(e >> 17);
            int idx = atomicAdd(&posl[dlow], 1);
            colsrc[idx] = srcv;
        }
    }
}

// ---------------- GEMM: H = X @ W  (K = 64) ----------------
__global__ void gemm_k64_n64_kernel(const float* __restrict__ X, const float* __restrict__ W,
                                    float* __restrict__ H) {
    __shared__ float Ws[64 * 64];
    __shared__ float Xs[4][64];
    int tid = threadIdx.x;
    {
        const float4* Wv = (const float4*)W;
        float4* Wsv = (float4*)Ws;
#pragma unroll
        for (int i = 0; i < 4; ++i) Wsv[tid + 256 * i] = Wv[tid + 256 * i];
    }
    int row0 = blockIdx.x * 4;
    int r = tid >> 6;
    int col = tid & 63;
    Xs[r][col] = X[(row0 + r) * 64 + col];
    __syncthreads();

    float sum = 0.f;
#pragma unroll
    for (int k = 0; k < 64; ++k) sum += Xs[r][k] * Ws[k * 64 + col];
    H[(row0 + r) * 64 + col] = sum;
}

__global__ void gemm_k64_n32_kernel(const float* __restrict__ X, const float* __restrict__ W,
                                    float* __restrict__ H) {
    __shared__ float Ws[64 * 32];
    __shared__ float Xs[8][64];
    int tid = threadIdx.x;
    {
        const float4* Wv = (const float4*)W;
        float4* Wsv = (float4*)Ws;
#pragma unroll
        for (int i = 0; i < 2; ++i) Wsv[tid + 256 * i] = Wv[tid + 256 * i];
    }
    int row0 = blockIdx.x * 8;
    {
        int idx = tid;
#pragma unroll
        for (int i = 0; i < 2; ++i, idx += 256) Xs[idx >> 6][idx & 63] = X[row0 * 64 + idx];
    }
    __syncthreads();

    int r = tid >> 5;
    int col = tid & 31;
    float sum = 0.f;
#pragma unroll
    for (int k = 0; k < 64; ++k) sum += Xs[r][k] * Ws[k * 32 + col];
    H[(row0 + r) * 32 + col] = sum;
}

// ---------------- gather aggregation ----------------
__global__ void gather64_kernel(const float* __restrict__ H, const int* __restrict__ rowptr,
                                const int* __restrict__ colsrc, const float* __restrict__ dinv,
                                const float* __restrict__ bias, float* __restrict__ out) {
    int wid = (blockIdx.x * blockDim.x + threadIdx.x) >> 6;
    int lane = threadIdx.x & 63;
    if (wid >= N_NODES) return;
    int v = wid;
    float dv = dinv[v];
    int beg = rowptr[v], end = rowptr[v + 1];
    float acc = H[(size_t)v * 64 + lane] * dv * dv;  // self-loop
    float a1 = 0.f, a2 = 0.f, a3 = 0.f;
    for (int j0 = beg; j0 < end; j0 += 64) {
        int myj = j0 + lane;
        int s = 0;
        float w = 0.f;
        if (myj < end) {
            s = colsrc[myj];
            w = dinv[s] * dv;
        }
        int cnt = min(64, end - j0);
        int t = 0;
        for (; t + 4 <= cnt; t += 4) {
            int s0 = __shfl(s, t), s1 = __shfl(s, t + 1), s2 = __shfl(s, t + 2), s3 = __shfl(s, t + 3);
            float w0 = __shfl(w, t), w1 = __shfl(w, t + 1), w2 = __shfl(w, t + 2), w3 = __shfl(w, t + 3);
            acc += H[(size_t)s0 * 64 + lane] * w0;
            a1 += H[(size_t)s1 * 64 + lane] * w1;
            a2 += H[(size_t)s2 * 64 + lane] * w2;
            a3 += H[(size_t)s3 * 64 + lane] * w3;
        }
        for (; t < cnt; ++t) {
            int sv = __shfl(s, t);
            float wv = __shfl(w, t);
            acc += H[(size_t)sv * 64 + lane] * wv;
        }
    }
    acc = (acc + a1) + (a2 + a3);
    acc += bias[lane];
    acc = acc > 0.f ? acc : NEG_SLOPE * acc;
    out[(size_t)v * 64 + lane] = acc;
}

__global__ void gather32_kernel(const float* __restrict__ H, const int* __restrict__ rowptr,
                                const int* __restrict__ colsrc, const float* __restrict__ dinv,
                                const float* __restrict__ bias, float* __restrict__ out) {
    int gw = (blockIdx.x * blockDim.x + threadIdx.x) >> 5;
    int lane = threadIdx.x & 31;
    if (gw >= N_NODES) return;
    int v = gw;
    float dv = dinv[v];
    int beg = rowptr[v], end = rowptr[v + 1];
    float acc = H[(size_t)v * 32 + lane] * dv * dv;  // self-loop
    float a1 = 0.f, a2 = 0.f, a3 = 0.f;
    for (int j0 = beg; j0 < end; j0 += 32) {
        int myj = j0 + lane;
        int s = 0;
        float w = 0.f;
        if (myj < end) {
            s = colsrc[myj];
            w = dinv[s] * dv;
        }
        int cnt = min(32, end - j0);
        int t = 0;
        for (; t + 4 <= cnt; t += 4) {
            int s0 = __shfl(s, t, 32), s1 = __shfl(s, t + 1, 32), s2 = __shfl(s, t + 2, 32),
                s3 = __shfl(s, t + 3, 32);
            float w0 = __shfl(w, t, 32), w1 = __shfl(w, t + 1, 32), w2 = __shfl(w, t + 2, 32),
                  w3 = __shfl(w, t + 3, 32);
            acc += H[(size_t)s0 * 32 + lane] * w0;
            a1 += H[(size_t)s1 * 32 + lane] * w1;
            a2 += H[(size_t)s2 * 32 + lane] * w2;
            a3 += H[(size_t)s3 * 32 + lane] * w3;
        }
        for (; t < cnt; ++t) {
            int sv = __shfl(s, t, 32);
            float wv = __shfl(w, t, 32);
            acc += H[(size_t)sv * 32 + lane] * wv;
        }
    }
    acc = (acc + a1) + (a2 + a3);
    acc += bias[lane];
    out[(size_t)v * 32 + lane] = acc;
}

extern "C" void kernel_launch(void* const* d_in, const int* in_sizes, int n_in,
                              void* d_out, int out_size, void* d_ws, size_t ws_size,
                              hipStream_t stream) {
    const float* x = (const float*)d_in[0];
    const int* ei = (const int*)d_in[1];  // [2,E]: src row then dst row
    const float* W1 = (const float*)d_in[2];
    const float* b1 = (const float*)d_in[3];
    const float* W2 = (const float*)d_in[4];
    const float* b2 = (const float*)d_in[5];
    float* out = (float*)d_out;

    const int* src = ei;
    const int* dst = ei + N_EDGES;

    // workspace layout (~59 MB)
    float* dinv = (float*)d_ws;               // N
    int* rowptr = (int*)(dinv + N_NODES);     // N+1
    int* cnt = rowptr + N_NODES + 1;          // N
    int* bsum = cnt + N_NODES;                // NBLK
    int* bofs = bsum + NBLK;                  // NBLK
    int* subfill = bofs + NBLK;               // NBUCK*NSTRM
    int* colsrc = subfill + NBUCK * NSTRM;    // E
    float* h1 = (float*)(colsrc + N_EDGES);   // N*64
    float* h1p = h1 + (size_t)N_NODES * DIN;  // N*64
    unsigned int* tmp = (unsigned int*)h1;    // alias: tmp dead before gemm64 writes h1
    float* h2 = h1;                           // alias: h1/tmp dead after gather64

    // CSR build + norms
    zero_kernel<<<NBLK, 256, 0, stream>>>(cnt, subfill);
    count_kernel<<<(N_EDGES + 255) / 256, 256, 0, stream>>>(dst, cnt);
    blocksum_kernel<<<NBLK, 256, 0, stream>>>(cnt, bsum);
    scan_bsum_kernel<<<1, 512, 0, stream>>>(bsum, bofs);
    rowptr_kernel<<<NBLK, 256, 0, stream>>>(cnt, bofs, rowptr, dinv);
    binpass1_kernel<<<(N_EDGES + 255) / 256, 256, 0, stream>>>(src, dst, subfill, tmp);
    binpass2_kernel<<<NBUCK, 256, 0, stream>>>(tmp, subfill, rowptr, colsrc);

    // layer 1
    gemm_k64_n64_kernel<<<N_NODES / 4, 256, 0, stream>>>(x, W1, h1);
    gather64_kernel<<<(N_NODES * 64 + 255) / 256, 256, 0, stream>>>(h1, rowptr, colsrc, dinv, b1, h1p);

    // layer 2
    gemm_k64_n32_kernel<<<N_NODES / 8, 256, 0, stream>>>(h1p, W2, h2);
    gather32_kernel<<<(N_NODES * 32 + 255) / 256, 256, 0, stream>>>(h2, rowptr, colsrc, dinv, b2, out);
}

// Round 5
// 355.365 us; speedup vs baseline: 1.6230x; 1.6230x over previous
//
#include <hip/hip_runtime.h>

#define N_NODES 100000
#define N_EDGES 1600000
#define DIN 64
#define DOUT 32
#define NEG_SLOPE 0.01f
#define NBLK ((N_NODES + 255) / 256)  // 391
#define RANGE (N_NODES / 8)           // 12500 nodes per XCD range
#define GROUP_BLOCKS 512              // blocks per range-group
#define NCHUNK ((N_EDGES + 255) / 256)  // 6250

// ---------------- CSR build ----------------
__global__ void zero_cnt_kernel(int* __restrict__ cnt) {
    int i = blockIdx.x * blockDim.x + threadIdx.x;
    if (i < N_NODES) cnt[i] = 0;
}

// degree histogram, XCD-range partitioned: group g (blockIdx&7 ~ XCD) only
// touches cnt[g*RANGE, (g+1)*RANGE) -> histogram slice stays in that XCD's L2.
__global__ void count8_kernel(const int* __restrict__ dst, int* __restrict__ cnt) {
    int g = blockIdx.x & 7;
    int b = blockIdx.x >> 3;
    for (int c = b; c < NCHUNK; c += GROUP_BLOCKS) {
        int e = c * 256 + threadIdx.x;
        int d = dst[e];
        if (d / RANGE == g) atomicAdd(&cnt[d], 1);
    }
}

// phase A: per-block sums of cnt
__global__ void blocksum_kernel(const int* __restrict__ cnt, int* __restrict__ bsum) {
    int i = blockIdx.x * 256 + threadIdx.x;
    int v = (i < N_NODES) ? cnt[i] : 0;
#pragma unroll
    for (int off = 32; off; off >>= 1) v += __shfl_down(v, off);
    __shared__ int ws[4];
    if ((threadIdx.x & 63) == 0) ws[threadIdx.x >> 6] = v;
    __syncthreads();
    if (threadIdx.x == 0) bsum[blockIdx.x] = ws[0] + ws[1] + ws[2] + ws[3];
}

// phase B: exclusive scan of the 391 block sums
__global__ __launch_bounds__(512) void scan_bsum_kernel(const int* __restrict__ bsum,
                                                        int* __restrict__ bofs) {
    __shared__ int sh[512];
    int t = threadIdx.x;
    int v = (t < NBLK) ? bsum[t] : 0;
    sh[t] = v;
    __syncthreads();
    for (int off = 1; off < 512; off <<= 1) {
        int a = sh[t];
        int add = (t >= off) ? sh[t - off] : 0;
        __syncthreads();
        sh[t] = a + add;
        __syncthreads();
    }
    if (t < NBLK) bofs[t] = sh[t] - v;  // exclusive
}

// phase C: in-block exclusive scan + block offset -> rowptr, pos, dinv
__global__ void rowptr_kernel(const int* __restrict__ cnt, const int* __restrict__ bofs,
                              int* __restrict__ rowptr, int* __restrict__ pos,
                              float* __restrict__ dinv) {
    int i = blockIdx.x * 256 + threadIdx.x;
    int v = (i < N_NODES) ? cnt[i] : 0;
    int lane = threadIdx.x & 63;
    int w = threadIdx.x >> 6;
    int x = v;
#pragma unroll
    for (int off = 1; off < 64; off <<= 1) {
        int n = __shfl_up(x, off);
        if (lane >= off) x += n;
    }
    __shared__ int wtot[4];
    if (lane == 63) wtot[w] = x;
    __syncthreads();
    int wofs = 0;
    for (int k = 0; k < w; ++k) wofs += wtot[k];
    int excl = x - v + wofs + bofs[blockIdx.x];
    if (i < N_NODES) {
        rowptr[i] = excl;
        pos[i] = excl;
        dinv[i] = rsqrtf((float)(v + 1));
        if (i == N_NODES - 1) rowptr[N_NODES] = excl + v;
    }
}

// CSR fill, XCD-range partitioned: group g only fills rows in its node range,
// so pos-slice atomics and colsrc-slice writes stay in one XCD's L2 and each
// 64B line collects all its writes before a single write-back.
__global__ void fill8_kernel(const int* __restrict__ src, const int* __restrict__ dst,
                             int* __restrict__ pos, int* __restrict__ colsrc) {
    int g = blockIdx.x & 7;
    int b = blockIdx.x >> 3;
    for (int c = b; c < NCHUNK; c += GROUP_BLOCKS) {
        int e = c * 256 + threadIdx.x;
        int d = dst[e];
        if (d / RANGE == g) {
            int idx = atomicAdd(&pos[d], 1);
            colsrc[idx] = src[e];
        }
    }
}

// ---------------- GEMM: H = X @ W  (K = 64) ----------------
__global__ void gemm_k64_n64_kernel(const float* __restrict__ X, const float* __restrict__ W,
                                    float* __restrict__ H) {
    __shared__ float Ws[64 * 64];
    __shared__ float Xs[4][64];
    int tid = threadIdx.x;
    {
        const float4* Wv = (const float4*)W;
        float4* Wsv = (float4*)Ws;
#pragma unroll
        for (int i = 0; i < 4; ++i) Wsv[tid + 256 * i] = Wv[tid + 256 * i];
    }
    int row0 = blockIdx.x * 4;
    int r = tid >> 6;
    int col = tid & 63;
    Xs[r][col] = X[(row0 + r) * 64 + col];
    __syncthreads();

    float sum = 0.f;
#pragma unroll
    for (int k = 0; k < 64; ++k) sum += Xs[r][k] * Ws[k * 64 + col];
    H[(row0 + r) * 64 + col] = sum;
}

__global__ void gemm_k64_n32_kernel(const float* __restrict__ X, const float* __restrict__ W,
                                    float* __restrict__ H) {
    __shared__ float Ws[64 * 32];
    __shared__ float Xs[8][64];
    int tid = threadIdx.x;
    {
        const float4* Wv = (const float4*)W;
        float4* Wsv = (float4*)Ws;
#pragma unroll
        for (int i = 0; i < 2; ++i) Wsv[tid + 256 * i] = Wv[tid + 256 * i];
    }
    int row0 = blockIdx.x * 8;
    {
        int idx = tid;
#pragma unroll
        for (int i = 0; i < 2; ++i, idx += 256) Xs[idx >> 6][idx & 63] = X[row0 * 64 + idx];
    }
    __syncthreads();

    int r = tid >> 5;
    int col = tid & 31;
    float sum = 0.f;
#pragma unroll
    for (int k = 0; k < 64; ++k) sum += Xs[r][k] * Ws[k * 32 + col];
    H[(row0 + r) * 32 + col] = sum;
}

// ---------------- gather aggregation ----------------
__global__ void gather64_kernel(const float* __restrict__ H, const int* __restrict__ rowptr,
                                const int* __restrict__ colsrc, const float* __restrict__ dinv,
                                const float* __restrict__ bias, float* __restrict__ out) {
    int wid = (blockIdx.x * blockDim.x + threadIdx.x) >> 6;
    int lane = threadIdx.x & 63;
    if (wid >= N_NODES) return;
    int v = wid;
    float dv = dinv[v];
    int beg = rowptr[v], end = rowptr[v + 1];
    float acc = H[(size_t)v * 64 + lane] * dv * dv;  // self-loop
    float a1 = 0.f, a2 = 0.f, a3 = 0.f;
    for (int j0 = beg; j0 < end; j0 += 64) {
        int myj = j0 + lane;
        int s = 0;
        float w = 0.f;
        if (myj < end) {
            s = colsrc[myj];
            w = dinv[s] * dv;
        }
        int cnt = min(64, end - j0);
        int t = 0;
        for (; t + 4 <= cnt; t += 4) {
            int s0 = __shfl(s, t), s1 = __shfl(s, t + 1), s2 = __shfl(s, t + 2), s3 = __shfl(s, t + 3);
            float w0 = __shfl(w, t), w1 = __shfl(w, t + 1), w2 = __shfl(w, t + 2), w3 = __shfl(w, t + 3);
            acc += H[(size_t)s0 * 64 + lane] * w0;
            a1 += H[(size_t)s1 * 64 + lane] * w1;
            a2 += H[(size_t)s2 * 64 + lane] * w2;
            a3 += H[(size_t)s3 * 64 + lane] * w3;
        }
        for (; t < cnt; ++t) {
            int sv = __shfl(s, t);
            float wv = __shfl(w, t);
            acc += H[(size_t)sv * 64 + lane] * wv;
        }
    }
    acc = (acc + a1) + (a2 + a3);
    acc += bias[lane];
    acc = acc > 0.f ? acc : NEG_SLOPE * acc;
    out[(size_t)v * 64 + lane] = acc;
}

__global__ void gather32_kernel(const float* __restrict__ H, const int* __restrict__ rowptr,
                                const int* __restrict__ colsrc, const float* __restrict__ dinv,
                                const float* __restrict__ bias, float* __restrict__ out) {
    int gw = (blockIdx.x * blockDim.x + threadIdx.x) >> 5;
    int lane = threadIdx.x & 31;
    if (gw >= N_NODES) return;
    int v = gw;
    float dv = dinv[v];
    int beg = rowptr[v], end = rowptr[v + 1];
    float acc = H[(size_t)v * 32 + lane] * dv * dv;  // self-loop
    float a1 = 0.f, a2 = 0.f, a3 = 0.f;
    for (int j0 = beg; j0 < end; j0 += 32) {
        int myj = j0 + lane;
        int s = 0;
        float w = 0.f;
        if (myj < end) {
            s = colsrc[myj];
            w = dinv[s] * dv;
        }
        int cnt = min(32, end - j0);
        int t = 0;
        for (; t + 4 <= cnt; t += 4) {
            int s0 = __shfl(s, t, 32), s1 = __shfl(s, t + 1, 32), s2 = __shfl(s, t + 2, 32),
                s3 = __shfl(s, t + 3, 32);
            float w0 = __shfl(w, t, 32), w1 = __shfl(w, t + 1, 32), w2 = __shfl(w, t + 2, 32),
                  w3 = __shfl(w, t + 3, 32);
            acc += H[(size_t)s0 * 32 + lane] * w0;
            a1 += H[(size_t)s1 * 32 + lane] * w1;
            a2 += H[(size_t)s2 * 32 + lane] * w2;
            a3 += H[(size_t)s3 * 32 + lane] * w3;
        }
        for (; t < cnt; ++t) {
            int sv = __shfl(s, t, 32);
            float wv = __shfl(w, t, 32);
            acc += H[(size_t)sv * 32 + lane] * wv;
        }
    }
    acc = (acc + a1) + (a2 + a3);
    acc += bias[lane];
    out[(size_t)v * 32 + lane] = acc;
}

extern "C" void kernel_launch(void* const* d_in, const int* in_sizes, int n_in,
                              void* d_out, int out_size, void* d_ws, size_t ws_size,
                              hipStream_t stream) {
    const float* x = (const float*)d_in[0];
    const int* ei = (const int*)d_in[1];  // [2,E]: src row then dst row
    const float* W1 = (const float*)d_in[2];
    const float* b1 = (const float*)d_in[3];
    const float* W2 = (const float*)d_in[4];
    const float* b2 = (const float*)d_in[5];
    float* out = (float*)d_out;

    const int* src = ei;
    const int* dst = ei + N_EDGES;

    // workspace layout (~58 MB)
    float* dinv = (float*)d_ws;               // N
    int* rowptr = (int*)(dinv + N_NODES);     // N+1
    int* cnt = rowptr + N_NODES + 1;          // N
    int* pos = cnt + N_NODES;                 // N
    int* bsum = pos + N_NODES;                // NBLK
    int* bofs = bsum + NBLK;                  // NBLK
    int* colsrc = bofs + NBLK;                // E
    float* h1 = (float*)(colsrc + N_EDGES);   // N*64
    float* h1p = h1 + (size_t)N_NODES * DIN;  // N*64
    float* h2 = h1;                           // alias: h1 dead after gather64

    // CSR build + norms
    zero_cnt_kernel<<<NBLK, 256, 0, stream>>>(cnt);
    count8_kernel<<<8 * GROUP_BLOCKS, 256, 0, stream>>>(dst, cnt);
    blocksum_kernel<<<NBLK, 256, 0, stream>>>(cnt, bsum);
    scan_bsum_kernel<<<1, 512, 0, stream>>>(bsum, bofs);
    rowptr_kernel<<<NBLK, 256, 0, stream>>>(cnt, bofs, rowptr, pos, dinv);
    fill8_kernel<<<8 * GROUP_BLOCKS, 256, 0, stream>>>(src, dst, pos, colsrc);

    // layer 1
    gemm_k64_n64_kernel<<<N_NODES / 4, 256, 0, stream>>>(x, W1, h1);
    gather64_kernel<<<(N_NODES * 64 + 255) / 256, 256, 0, stream>>>(h1, rowptr, colsrc, dinv, b1, h1p);

    // layer 2
    gemm_k64_n32_kernel<<<N_NODES / 8, 256, 0, stream>>>(h1p, W2, h2);
    gather32_kernel<<<(N_NODES * 32 + 255) / 256, 256, 0, stream>>>(h2, rowptr, colsrc, dinv, b2, out);
}

// Round 6
// 313.125 us; speedup vs baseline: 1.8420x; 1.1349x over previous
//
#include <hip/hip_runtime.h>

#define N_NODES 100000
#define N_EDGES 1600000
#define DIN 64
#define DOUT 32
#define NEG_SLOPE 0.01f
#define NBLK ((N_NODES + 255) / 256)  // 391
#define RANGE (N_NODES / 8)           // 12500 nodes per XCD range
#define GROUP_BLOCKS 512              // blocks per range-group
#define NCHUNK ((N_EDGES + 255) / 256)  // 6250

__device__ inline unsigned short f2bf(float f) {  // RNE
    unsigned int u = __float_as_uint(f);
    unsigned int r = (u + 0x7fffu + ((u >> 16) & 1u)) >> 16;
    return (unsigned short)r;
}
__device__ inline float bflo(unsigned int p) { return __uint_as_float(p << 16); }
__device__ inline float bfhi(unsigned int p) { return __uint_as_float(p & 0xffff0000u); }

// ---------------- CSR build ----------------
__global__ void zero_cnt_kernel(int* __restrict__ cnt) {
    int i = blockIdx.x * blockDim.x + threadIdx.x;
    if (i < N_NODES) cnt[i] = 0;
}

// degree histogram, XCD-range partitioned (group g = blockIdx&7 ~ XCD)
__global__ void count8_kernel(const int* __restrict__ dst, int* __restrict__ cnt) {
    int g = blockIdx.x & 7;
    int b = blockIdx.x >> 3;
    int lo = g * RANGE;
    for (int c = b; c < NCHUNK; c += GROUP_BLOCKS) {
        int e = c * 256 + threadIdx.x;
        int d = dst[e];
        if ((unsigned)(d - lo) < (unsigned)RANGE) atomicAdd(&cnt[d], 1);
    }
}

__global__ void blocksum_kernel(const int* __restrict__ cnt, int* __restrict__ bsum) {
    int i = blockIdx.x * 256 + threadIdx.x;
    int v = (i < N_NODES) ? cnt[i] : 0;
#pragma unroll
    for (int off = 32; off; off >>= 1) v += __shfl_down(v, off);
    __shared__ int ws[4];
    if ((threadIdx.x & 63) == 0) ws[threadIdx.x >> 6] = v;
    __syncthreads();
    if (threadIdx.x == 0) bsum[blockIdx.x] = ws[0] + ws[1] + ws[2] + ws[3];
}

__global__ __launch_bounds__(512) void scan_bsum_kernel(const int* __restrict__ bsum,
                                                        int* __restrict__ bofs) {
    __shared__ int sh[512];
    int t = threadIdx.x;
    int v = (t < NBLK) ? bsum[t] : 0;
    sh[t] = v;
    __syncthreads();
    for (int off = 1; off < 512; off <<= 1) {
        int a = sh[t];
        int add = (t >= off) ? sh[t - off] : 0;
        __syncthreads();
        sh[t] = a + add;
        __syncthreads();
    }
    if (t < NBLK) bofs[t] = sh[t] - v;  // exclusive
}

__global__ void rowptr_kernel(const int* __restrict__ cnt, const int* __restrict__ bofs,
                              int* __restrict__ rowptr, int* __restrict__ pos,
                              float* __restrict__ dinv) {
    int i = blockIdx.x * 256 + threadIdx.x;
    int v = (i < N_NODES) ? cnt[i] : 0;
    int lane = threadIdx.x & 63;
    int w = threadIdx.x >> 6;
    int x = v;
#pragma unroll
    for (int off = 1; off < 64; off <<= 1) {
        int n = __shfl_up(x, off);
        if (lane >= off) x += n;
    }
    __shared__ int wtot[4];
    if (lane == 63) wtot[w] = x;
    __syncthreads();
    int wofs = 0;
    for (int k = 0; k < w; ++k) wofs += wtot[k];
    int excl = x - v + wofs + bofs[blockIdx.x];
    if (i < N_NODES) {
        rowptr[i] = excl;
        pos[i] = excl;
        dinv[i] = rsqrtf((float)(v + 1));
        if (i == N_NODES - 1) rowptr[N_NODES] = excl + v;
    }
}

// CSR fill, XCD-range partitioned
__global__ void fill8_kernel(const int* __restrict__ src, const int* __restrict__ dst,
                             int* __restrict__ pos, int* __restrict__ colsrc) {
    int g = blockIdx.x & 7;
    int b = blockIdx.x >> 3;
    int lo = g * RANGE;
    for (int c = b; c < NCHUNK; c += GROUP_BLOCKS) {
        int e = c * 256 + threadIdx.x;
        int d = dst[e];
        if ((unsigned)(d - lo) < (unsigned)RANGE) {
            int idx = atomicAdd(&pos[d], 1);
            colsrc[idx] = src[e];
        }
    }
}

// ---------------- GEMM: Hn = (X @ W) * dinv[row], bf16 out ----------------
__global__ void gemm_k64_n64_kernel(const float* __restrict__ X, const float* __restrict__ W,
                                    const float* __restrict__ dinv,
                                    unsigned short* __restrict__ Hn) {
    __shared__ float Ws[64 * 64];
    __shared__ float Xs[4][64];
    int tid = threadIdx.x;
    {
        const float4* Wv = (const float4*)W;
        float4* Wsv = (float4*)Ws;
#pragma unroll
        for (int i = 0; i < 4; ++i) Wsv[tid + 256 * i] = Wv[tid + 256 * i];
    }
    int row0 = blockIdx.x * 4;
    int r = tid >> 6;
    int col = tid & 63;
    Xs[r][col] = X[(row0 + r) * 64 + col];
    __syncthreads();

    float sum = 0.f;
#pragma unroll
    for (int k = 0; k < 64; ++k) sum += Xs[r][k] * Ws[k * 64 + col];
    Hn[(row0 + r) * 64 + col] = f2bf(sum * dinv[row0 + r]);
}

__global__ void gemm_k64_n32_kernel(const float* __restrict__ X, const float* __restrict__ W,
                                    const float* __restrict__ dinv,
                                    unsigned short* __restrict__ Hn) {
    __shared__ float Ws[64 * 32];
    __shared__ float Xs[8][64];
    int tid = threadIdx.x;
    {
        const float4* Wv = (const float4*)W;
        float4* Wsv = (float4*)Ws;
#pragma unroll
        for (int i = 0; i < 2; ++i) Wsv[tid + 256 * i] = Wv[tid + 256 * i];
    }
    int row0 = blockIdx.x * 8;
    {
        int idx = tid;
#pragma unroll
        for (int i = 0; i < 2; ++i, idx += 256) Xs[idx >> 6][idx & 63] = X[row0 * 64 + idx];
    }
    __syncthreads();

    int r = tid >> 5;
    int col = tid & 31;
    float sum = 0.f;
#pragma unroll
    for (int k = 0; k < 64; ++k) sum += Xs[r][k] * Ws[k * 32 + col];
    Hn[(row0 + r) * 32 + col] = f2bf(sum * dinv[row0 + r]);
}

// ---------------- gather aggregation (bf16 rows, norm pre-folded) ----------------
// out[v] = leaky(dinv[v] * (sum_{s in nbr} Hn[s] + Hn[v]) + b)
// wave per node; half-wave h handles its half of the edge list; lane owns dims (2sl, 2sl+1)
__global__ void gather64_kernel(const unsigned short* __restrict__ Hn,
                                const int* __restrict__ rowptr, const int* __restrict__ colsrc,
                                const float* __restrict__ dinv, const float* __restrict__ bias,
                                float* __restrict__ out) {
    int wid = (blockIdx.x * blockDim.x + threadIdx.x) >> 6;
    int lane = threadIdx.x & 63;
    if (wid >= N_NODES) return;
    int v = wid;
    int half = lane >> 5;
    int sl = lane & 31;
    int hb = half << 5;
    int beg = rowptr[v], end = rowptr[v + 1];
    int len = end - beg;
    int mid = beg + ((len + 1) >> 1);
    int l0 = half ? mid : beg;
    int l1 = half ? end : mid;

    float acc0 = 0.f, acc1 = 0.f, b0 = 0.f, b1 = 0.f;
    if (half == 0) {  // self row once
        unsigned int rw = ((const unsigned int*)(Hn + (size_t)v * 64))[sl];
        acc0 = bflo(rw);
        acc1 = bfhi(rw);
    }
    for (int j0 = l0; j0 < l1; j0 += 32) {
        int myj = j0 + sl;
        int s = (myj < l1) ? colsrc[myj] : 0;
        int cnt = min(32, l1 - j0);
        int t = 0;
        for (; t + 2 <= cnt; t += 2) {
            int s0 = __shfl(s, hb + t);
            int s1 = __shfl(s, hb + t + 1);
            unsigned int r0 = ((const unsigned int*)(Hn + (size_t)s0 * 64))[sl];
            unsigned int r1 = ((const unsigned int*)(Hn + (size_t)s1 * 64))[sl];
            acc0 += bflo(r0);
            acc1 += bfhi(r0);
            b0 += bflo(r1);
            b1 += bfhi(r1);
        }
        if (t < cnt) {
            int s0 = __shfl(s, hb + t);
            unsigned int r0 = ((const unsigned int*)(Hn + (size_t)s0 * 64))[sl];
            acc0 += bflo(r0);
            acc1 += bfhi(r0);
        }
    }
    acc0 += b0;
    acc1 += b1;
    acc0 += __shfl_xor(acc0, 32);
    acc1 += __shfl_xor(acc1, 32);
    if (half == 0) {
        float dv = dinv[v];
        float2 bb = ((const float2*)bias)[sl];
        float o0 = acc0 * dv + bb.x;
        float o1 = acc1 * dv + bb.y;
        o0 = o0 > 0.f ? o0 : NEG_SLOPE * o0;
        o1 = o1 > 0.f ? o1 : NEG_SLOPE * o1;
        ((float2*)(out + (size_t)v * 64))[sl] = make_float2(o0, o1);
    }
}

// wave per node; quarter-wave q handles its quarter of the edges; lane owns dims (2sl, 2sl+1), sl<16
__global__ void gather32_kernel(const unsigned short* __restrict__ Hn,
                                const int* __restrict__ rowptr, const int* __restrict__ colsrc,
                                const float* __restrict__ dinv, const float* __restrict__ bias,
                                float* __restrict__ out) {
    int wid = (blockIdx.x * blockDim.x + threadIdx.x) >> 6;
    int lane = threadIdx.x & 63;
    if (wid >= N_NODES) return;
    int v = wid;
    int q = lane >> 4;
    int sl = lane & 15;
    int qb = q << 4;
    int beg = rowptr[v], end = rowptr[v + 1];
    int len = end - beg;
    int qs = (len + 3) >> 2;
    int l0 = beg + min(len, qs * q);
    int l1 = beg + min(len, qs * (q + 1));

    float acc0 = 0.f, acc1 = 0.f, b0 = 0.f, b1 = 0.f;
    if (q == 0) {  // self row once
        unsigned int rw = ((const unsigned int*)(Hn + (size_t)v * 32))[sl];
        acc0 = bflo(rw);
        acc1 = bfhi(rw);
    }
    for (int j0 = l0; j0 < l1; j0 += 16) {
        int myj = j0 + sl;
        int s = (myj < l1) ? colsrc[myj] : 0;
        int cnt = min(16, l1 - j0);
        int t = 0;
        for (; t + 2 <= cnt; t += 2) {
            int s0 = __shfl(s, qb + t);
            int s1 = __shfl(s, qb + t + 1);
            unsigned int r0 = ((const unsigned int*)(Hn + (size_t)s0 * 32))[sl];
            unsigned int r1 = ((const unsigned int*)(Hn + (size_t)s1 * 32))[sl];
            acc0 += bflo(r0);
            acc1 += bfhi(r0);
            b0 += bflo(r1);
            b1 += bfhi(r1);
        }
        if (t < cnt) {
            int s0 = __shfl(s, qb + t);
            unsigned int r0 = ((const unsigned int*)(Hn + (size_t)s0 * 32))[sl];
            acc0 += bflo(r0);
            acc1 += bfhi(r0);
        }
    }
    acc0 += b0;
    acc1 += b1;
    acc0 += __shfl_xor(acc0, 16);
    acc1 += __shfl_xor(acc1, 16);
    acc0 += __shfl_xor(acc0, 32);
    acc1 += __shfl_xor(acc1, 32);
    if (q == 0) {
        float dv = dinv[v];
        float2 bb = ((const float2*)bias)[sl];
        float o0 = acc0 * dv + bb.x;
        float o1 = acc1 * dv + bb.y;
        ((float2*)(out + (size_t)v * 32))[sl] = make_float2(o0, o1);
    }
}

extern "C" void kernel_launch(void* const* d_in, const int* in_sizes, int n_in,
                              void* d_out, int out_size, void* d_ws, size_t ws_size,
                              hipStream_t stream) {
    const float* x = (const float*)d_in[0];
    const int* ei = (const int*)d_in[1];  // [2,E]: src row then dst row
    const float* W1 = (const float*)d_in[2];
    const float* b1 = (const float*)d_in[3];
    const float* W2 = (const float*)d_in[4];
    const float* b2 = (const float*)d_in[5];
    float* out = (float*)d_out;

    const int* src = ei;
    const int* dst = ei + N_EDGES;

    // workspace layout (~47 MB)
    float* dinv = (float*)d_ws;                       // N
    int* rowptr = (int*)(dinv + N_NODES);             // N+1
    int* cnt = rowptr + N_NODES + 1;                  // N
    int* pos = cnt + N_NODES;                         // N
    int* bsum = pos + N_NODES;                        // NBLK
    int* bofs = bsum + NBLK;                          // NBLK
    int* colsrc = bofs + NBLK;                        // E
    unsigned short* h1n = (unsigned short*)(colsrc + N_EDGES);  // N*64 bf16
    float* h1p = (float*)(h1n + (size_t)N_NODES * DIN);         // N*64 f32
    unsigned short* h2n = h1n;  // alias: h1n dead after gather64

    // CSR build + norms
    zero_cnt_kernel<<<NBLK, 256, 0, stream>>>(cnt);
    count8_kernel<<<8 * GROUP_BLOCKS, 256, 0, stream>>>(dst, cnt);
    blocksum_kernel<<<NBLK, 256, 0, stream>>>(cnt, bsum);
    scan_bsum_kernel<<<1, 512, 0, stream>>>(bsum, bofs);
    rowptr_kernel<<<NBLK, 256, 0, stream>>>(cnt, bofs, rowptr, pos, dinv);
    fill8_kernel<<<8 * GROUP_BLOCKS, 256, 0, stream>>>(src, dst, pos, colsrc);

    // layer 1
    gemm_k64_n64_kernel<<<N_NODES / 4, 256, 0, stream>>>(x, W1, dinv, h1n);
    gather64_kernel<<<(N_NODES * 64 + 255) / 256, 256, 0, stream>>>(h1n, rowptr, colsrc, dinv, b1, h1p);

    // layer 2
    gemm_k64_n32_kernel<<<N_NODES / 8, 256, 0, stream>>>(h1p, W2, dinv, h2n);
    gather32_kernel<<<(N_NODES * 64 + 255) / 256, 256, 0, stream>>>(h2n, rowptr, colsrc, dinv, b2, out);
}